// Round 3
// baseline (887.191 us; speedup 1.0000x reference)
//
#include <hip/hip_runtime.h>
#include <hip/hip_fp16.h>

typedef _Float16 half_t;
typedef __attribute__((ext_vector_type(4))) _Float16 f16x4;
typedef __attribute__((ext_vector_type(8))) _Float16 f16x8;
typedef __attribute__((ext_vector_type(4))) float f32x4;

#define WAVES_PER_BLOCK 16
#define MAIN_BLOCK 1024
#define MAIN_GRID 512

// ---------------------------------------------------------------------------
// Prep: z (fp32, [N_NODES,128]) -> zh (f16, row-contiguous, for A gathers)
// ---------------------------------------------------------------------------
__global__ void prep_z_kernel(const float* __restrict__ z,
                              half_t* __restrict__ zh, int n4) {
    int t = blockIdx.x * 256 + threadIdx.x;
    if (t < n4) {
        const float4 v = reinterpret_cast<const float4*>(z)[t];
        f16x4 o;
        o[0] = (_Float16)v.x; o[1] = (_Float16)v.y;
        o[2] = (_Float16)v.z; o[3] = (_Float16)v.w;
        reinterpret_cast<f16x4*>(zh)[t] = o;
    }
}

// ---------------------------------------------------------------------------
// Main: each wave computes a 16-edge x 128-H tile (M=16 keeps acc at 32 VGPRs
// -> no spill; R2's 32-edge tile spilled acc to scratch = 585 MB writes).
//   W1 f32->f16 swizzled into MFMA B-fragment order in LDS once per block.
//   B-fragment (ks, nt): lane L, elem j holds
//     W1[k = ks*32 + (L>>4)*8 + j][n = nt*16 + (L&15)]
//   flat f16 LDS index = ((ks*8 + nt)*64 + L)*8 + j -> ds_read_b128,
//   consecutive lanes = consecutive 16B (conflict-free).
//   A: full src+dst rows (8 x 16B/lane) prefetched in ONE burst per group ->
//   single latency exposure, no L2 line thrash between k-chunks.
//   Epilogue: bias + relu + dot(W2) fused, quad shfl_xor reduction.
// ---------------------------------------------------------------------------
template <bool F16Z>
__global__ __launch_bounds__(MAIN_BLOCK, 4)
void edge_mlp_kernel(const float* __restrict__ z,
                     const half_t* __restrict__ zh,
                     const int* __restrict__ eidx,
                     const float* __restrict__ W1,
                     const float* __restrict__ b1,
                     const float* __restrict__ W2,
                     const float* __restrict__ b2,
                     float* __restrict__ out,
                     int n_edges, int n_groups, int stride_groups) {
    __shared__ __align__(16) half_t w1_lds[32768];   // 64 KB
    // Stage + swizzle W1: coalesced fp32 reads, scattered f16 LDS writes.
#pragma unroll
    for (int i = 0; i < 32; ++i) {
        const int u = threadIdx.x + i * MAIN_BLOCK;  // flat k*128+n, 0..32767
        const int k = u >> 7, n = u & 127;
        const int t = (((k >> 5) * 8 + (n >> 4)) * 64 +
                       ((k >> 3) & 3) * 16 + (n & 15)) * 8 + (k & 7);
        w1_lds[t] = (half_t)W1[u];
    }
    __syncthreads();

    const int wave = threadIdx.x >> 6;
    const int lane = threadIdx.x & 63;
    const int nlo  = lane & 15;     // = edge-within-group = A row m
    const int quad = lane >> 4;     // k-subchunk within a 32-wide slice

    float b1v[8], w2v[8];
#pragma unroll
    for (int nt = 0; nt < 8; ++nt) {
        b1v[nt] = b1[nt * 16 + nlo];
        w2v[nt] = W2[nt * 16 + nlo];
    }
    const float b2v = b2[0];

    const f16x8* blds = reinterpret_cast<const f16x8*>(w1_lds);

    int g = blockIdx.x * WAVES_PER_BLOCK + wave;
    if (g >= n_groups) return;

    // indices for first group (prefetched each iteration thereafter)
    int em = g * 16 + nlo;
    if (em >= n_edges) em = n_edges - 1;
    int si = eidx[em];
    int di = eidx[n_edges + em];

    for (; g < n_groups; g += stride_groups) {
        const int e0 = g * 16;

        // ---- A prefetch: full src row + full dst row, one burst ----
        const half_t* ps = (F16Z ? zh : (const half_t*)nullptr);
        f16x8 av[8];
        if (F16Z) {
            const half_t* p0 = zh + (size_t)si * 128 + quad * 8;
            const half_t* p1 = zh + (size_t)di * 128 + quad * 8;
#pragma unroll
            for (int s = 0; s < 4; ++s) {
                av[s]     = *reinterpret_cast<const f16x8*>(p0 + s * 32);
                av[4 + s] = *reinterpret_cast<const f16x8*>(p1 + s * 32);
            }
        } else {
            const float* p0 = z + (size_t)si * 128 + quad * 8;
            const float* p1 = z + (size_t)di * 128 + quad * 8;
#pragma unroll
            for (int s = 0; s < 8; ++s) {
                const float4 va = reinterpret_cast<const float4*>(
                    (s < 4 ? p0 + s * 32 : p1 + (s - 4) * 32))[0];
                const float4 vb = reinterpret_cast<const float4*>(
                    (s < 4 ? p0 + s * 32 : p1 + (s - 4) * 32))[1];
                av[s][0] = (_Float16)va.x; av[s][1] = (_Float16)va.y;
                av[s][2] = (_Float16)va.z; av[s][3] = (_Float16)va.w;
                av[s][4] = (_Float16)vb.x; av[s][5] = (_Float16)vb.y;
                av[s][6] = (_Float16)vb.z; av[s][7] = (_Float16)vb.w;
            }
        }
        (void)ps;

        // ---- prefetch next group's edge indices (hides index latency) ----
        const int gn = g + stride_groups;
        if (gn < n_groups) {
            int emn = gn * 16 + nlo;
            if (emn >= n_edges) emn = n_edges - 1;
            si = eidx[emn];
            di = eidx[n_edges + emn];
        }

        // ---- MFMA main loop: 8 ks x 8 nt ----
        f32x4 acc[8];
#pragma unroll
        for (int nt = 0; nt < 8; ++nt)
            acc[nt] = (f32x4){0.f, 0.f, 0.f, 0.f};

#pragma unroll
        for (int ks = 0; ks < 8; ++ks) {
            const f16x8* bp = blds + ks * 512 + lane;
#pragma unroll
            for (int nt = 0; nt < 8; ++nt) {
                acc[nt] = __builtin_amdgcn_mfma_f32_16x16x32_f16(
                    av[ks], bp[nt * 64], acc[nt], 0, 0, 0);
            }
        }

        // ---- Epilogue: out[e] = b2 + sum_n relu(h[e][n] + b1[n]) * W2[n]
        // C/D layout: n = nt*16 + nlo, m = quad*4 + r.
#pragma unroll
        for (int r = 0; r < 4; ++r) {
            float s = 0.f;
#pragma unroll
            for (int nt = 0; nt < 8; ++nt) {
                const float h = acc[nt][r] + b1v[nt];
                s = fmaf(fmaxf(h, 0.f), w2v[nt], s);
            }
            s += __shfl_xor(s, 1);
            s += __shfl_xor(s, 2);
            s += __shfl_xor(s, 4);
            s += __shfl_xor(s, 8);
            const int e = e0 + quad * 4 + r;
            if (nlo == r && e < n_edges)
                out[e] = s + b2v;
        }
    }
}

extern "C" void kernel_launch(void* const* d_in, const int* in_sizes, int n_in,
                              void* d_out, int out_size, void* d_ws,
                              size_t ws_size, hipStream_t stream) {
    const float* z   = (const float*)d_in[0];
    const int* eidx  = (const int*)d_in[1];   // harness passes int64 ref as int32
    const float* W1  = (const float*)d_in[2];
    const float* b1  = (const float*)d_in[3];
    const float* W2  = (const float*)d_in[4];
    const float* b2  = (const float*)d_in[5];
    float* out       = (float*)d_out;

    const int nz      = in_sizes[0];      // 12,800,000 (N_NODES*128)
    const int n_edges = in_sizes[1] / 2;  // 1,000,000

    const int n_groups = (n_edges + 15) / 16;
    const int stride_groups = MAIN_GRID * WAVES_PER_BLOCK;

    const size_t zh_bytes = (size_t)nz * sizeof(half_t);
    if (ws_size >= zh_bytes) {
        half_t* zh = (half_t*)d_ws;
        const int n4 = nz / 4;
        prep_z_kernel<<<(n4 + 255) / 256, 256, 0, stream>>>(z, zh, n4);
        edge_mlp_kernel<true><<<MAIN_GRID, MAIN_BLOCK, 0, stream>>>(
            z, zh, eidx, W1, b1, W2, b2, out, n_edges, n_groups, stride_groups);
    } else {
        edge_mlp_kernel<false><<<MAIN_GRID, MAIN_BLOCK, 0, stream>>>(
            z, nullptr, eidx, W1, b1, W2, b2, out, n_edges, n_groups,
            stride_groups);
    }
}

// Round 4
// 397.884 us; speedup vs baseline: 2.2298x; 2.2298x over previous
//
#include <hip/hip_runtime.h>
#include <hip/hip_fp16.h>

typedef _Float16 half_t;
typedef __attribute__((ext_vector_type(4))) _Float16 f16x4;
typedef __attribute__((ext_vector_type(8))) _Float16 f16x8;
typedef __attribute__((ext_vector_type(4))) float f32x4;

// block = 256 (4 waves). LDS 64 KB -> 2 blocks/CU = 2 waves/SIMD -> 256-reg
// budget per wave on the unified VGPR/AGPR file. R2/R3 used block=1024 which
// forces >=4 waves/SIMD -> 128-reg cap -> acc/av spilled to scratch
// (WRITE_SIZE 474 MB matched 30 dwords x 64 lanes x 62500 iters exactly).
#define MAIN_BLOCK 256
#define WAVES_PER_BLOCK 4
#define MAIN_GRID 512

// ---------------------------------------------------------------------------
// Prep: z (fp32, [N_NODES,128]) -> zh (f16, row-contiguous, for A gathers)
// ---------------------------------------------------------------------------
__global__ void prep_z_kernel(const float* __restrict__ z,
                              half_t* __restrict__ zh, int n4) {
    int t = blockIdx.x * 256 + threadIdx.x;
    if (t < n4) {
        const float4 v = reinterpret_cast<const float4*>(z)[t];
        f16x4 o;
        o[0] = (_Float16)v.x; o[1] = (_Float16)v.y;
        o[2] = (_Float16)v.z; o[3] = (_Float16)v.w;
        reinterpret_cast<f16x4*>(zh)[t] = o;
    }
}

// ---------------------------------------------------------------------------
// Main: each wave computes a 32-edge x 128-H tile (2 M-tiles of 16).
//   W1 f32->f16 swizzled into MFMA B-fragment order in LDS once per block.
//   B-fragment (ks, nt): lane L, elem j holds
//     W1[k = ks*32 + (L>>4)*8 + j][n = nt*16 + (L&15)]
//   flat f16 LDS index = ((ks*8 + nt)*64 + L)*8 + j -> ds_read_b128,
//   consecutive lanes = consecutive 16B (conflict-free).
//   A: full src+dst rows (16 x 16B/lane) burst-loaded per group; next-group
//   edge indices prefetched one iteration ahead.
//   Epilogue: bias + relu + dot(W2) fused, quad shfl_xor reduction.
// ---------------------------------------------------------------------------
template <bool F16Z>
__global__ __launch_bounds__(MAIN_BLOCK, 2)
void edge_mlp_kernel(const float* __restrict__ z,
                     const half_t* __restrict__ zh,
                     const int* __restrict__ eidx,
                     const float* __restrict__ W1,
                     const float* __restrict__ b1,
                     const float* __restrict__ W2,
                     const float* __restrict__ b2,
                     float* __restrict__ out,
                     int n_edges, int n_groups, int stride_groups) {
    __shared__ __align__(16) half_t w1_lds[32768];   // 64 KB
    // Stage + swizzle W1: coalesced float4 reads, f16 LDS writes 16 B apart
    // (2-way bank aliasing = free on gfx950).
    {
        const float4* W1v = reinterpret_cast<const float4*>(W1);
#pragma unroll
        for (int i = 0; i < 32; ++i) {
            const int q = threadIdx.x + i * MAIN_BLOCK;  // 0..8191 float4s
            const int u = q * 4;                         // flat k*128 + n
            const int k = u >> 7, n0 = u & 127;
            const float4 w = W1v[q];
            half_t* dst = &w1_lds[((((k >> 5) * 8 + (n0 >> 4)) * 64 +
                                    ((k >> 3) & 3) * 16) * 8) + (k & 7)];
            const int nl = n0 & 15;
            dst[(nl + 0) * 8] = (half_t)w.x;
            dst[(nl + 1) * 8] = (half_t)w.y;
            dst[(nl + 2) * 8] = (half_t)w.z;
            dst[(nl + 3) * 8] = (half_t)w.w;
        }
    }
    __syncthreads();

    const int wave = threadIdx.x >> 6;
    const int lane = threadIdx.x & 63;
    const int nlo  = lane & 15;     // edge-within-M-tile = A row m
    const int quad = lane >> 4;     // k-subchunk within a 32-wide K slice

    float b1v[8], w2v[8];
#pragma unroll
    for (int nt = 0; nt < 8; ++nt) {
        b1v[nt] = b1[nt * 16 + nlo];
        w2v[nt] = W2[nt * 16 + nlo];
    }
    const float b2v = b2[0];

    const f16x8* blds = reinterpret_cast<const f16x8*>(w1_lds);

    int g = blockIdx.x * WAVES_PER_BLOCK + wave;
    if (g >= n_groups) return;

    // Edge indices for the current group (prefetched one iteration ahead).
    int em0 = g * 32 + nlo;       if (em0 >= n_edges) em0 = n_edges - 1;
    int em1 = g * 32 + 16 + nlo;  if (em1 >= n_edges) em1 = n_edges - 1;
    int s0 = eidx[em0], s1 = eidx[em1];
    int d0 = eidx[n_edges + em0], d1 = eidx[n_edges + em1];

    for (; g < n_groups; g += stride_groups) {
        const int e0 = g * 32;

        // ---- A burst: 4 full rows (src/dst for both M-tiles), 16B/lane ----
        f16x8 av0[8], av1[8];
        if (F16Z) {
            const half_t* p0s = zh + (size_t)s0 * 128 + quad * 8;
            const half_t* p0d = zh + (size_t)d0 * 128 + quad * 8;
            const half_t* p1s = zh + (size_t)s1 * 128 + quad * 8;
            const half_t* p1d = zh + (size_t)d1 * 128 + quad * 8;
#pragma unroll
            for (int s = 0; s < 4; ++s) {
                av0[s]     = *reinterpret_cast<const f16x8*>(p0s + s * 32);
                av0[4 + s] = *reinterpret_cast<const f16x8*>(p0d + s * 32);
                av1[s]     = *reinterpret_cast<const f16x8*>(p1s + s * 32);
                av1[4 + s] = *reinterpret_cast<const f16x8*>(p1d + s * 32);
            }
        } else {
            const float* p0s = z + (size_t)s0 * 128 + quad * 8;
            const float* p0d = z + (size_t)d0 * 128 + quad * 8;
            const float* p1s = z + (size_t)s1 * 128 + quad * 8;
            const float* p1d = z + (size_t)d1 * 128 + quad * 8;
#pragma unroll
            for (int s = 0; s < 4; ++s) {
                const float* q0 = p0s + s * 32;
                const float* q1 = p0d + s * 32;
                const float* q2 = p1s + s * 32;
                const float* q3 = p1d + s * 32;
#pragma unroll
                for (int j = 0; j < 8; ++j) {
                    av0[s][j]     = (_Float16)q0[j];
                    av0[4 + s][j] = (_Float16)q1[j];
                    av1[s][j]     = (_Float16)q2[j];
                    av1[4 + s][j] = (_Float16)q3[j];
                }
            }
        }

        // ---- prefetch next group's edge indices ----
        const int gn = g + stride_groups;
        if (gn < n_groups) {
            em0 = gn * 32 + nlo;       if (em0 >= n_edges) em0 = n_edges - 1;
            em1 = gn * 32 + 16 + nlo;  if (em1 >= n_edges) em1 = n_edges - 1;
            s0 = eidx[em0]; s1 = eidx[em1];
            d0 = eidx[n_edges + em0]; d1 = eidx[n_edges + em1];
        }

        // ---- MFMA main loop: 8 ks x 8 nt x 2 M-tiles ----
        f32x4 acc0[8], acc1[8];
#pragma unroll
        for (int nt = 0; nt < 8; ++nt) {
            acc0[nt] = (f32x4){0.f, 0.f, 0.f, 0.f};
            acc1[nt] = (f32x4){0.f, 0.f, 0.f, 0.f};
        }

#pragma unroll
        for (int ks = 0; ks < 8; ++ks) {
            const f16x8* bp = blds + ks * 512 + lane;
#pragma unroll
            for (int nt = 0; nt < 8; ++nt) {
                const f16x8 bf = bp[nt * 64];
                acc0[nt] = __builtin_amdgcn_mfma_f32_16x16x32_f16(
                    av0[ks], bf, acc0[nt], 0, 0, 0);
                acc1[nt] = __builtin_amdgcn_mfma_f32_16x16x32_f16(
                    av1[ks], bf, acc1[nt], 0, 0, 0);
            }
        }

        // ---- Epilogue: out[e] = b2 + sum_n relu(h[e][n] + b1[n]) * W2[n]
        // C/D layout: n = nt*16 + nlo, m = mt*16 + quad*4 + r.
#pragma unroll
        for (int mt = 0; mt < 2; ++mt) {
#pragma unroll
            for (int r = 0; r < 4; ++r) {
                float s = 0.f;
#pragma unroll
                for (int nt = 0; nt < 8; ++nt) {
                    const float h = (mt ? acc1[nt][r] : acc0[nt][r]) + b1v[nt];
                    s = fmaf(fmaxf(h, 0.f), w2v[nt], s);
                }
                s += __shfl_xor(s, 1);
                s += __shfl_xor(s, 2);
                s += __shfl_xor(s, 4);
                s += __shfl_xor(s, 8);
                const int e = e0 + mt * 16 + quad * 4 + r;
                if (nlo == mt * 4 + r && e < n_edges)
                    out[e] = s + b2v;
            }
        }
    }
}

extern "C" void kernel_launch(void* const* d_in, const int* in_sizes, int n_in,
                              void* d_out, int out_size, void* d_ws,
                              size_t ws_size, hipStream_t stream) {
    const float* z   = (const float*)d_in[0];
    const int* eidx  = (const int*)d_in[1];   // harness passes int64 ref as int32
    const float* W1  = (const float*)d_in[2];
    const float* b1  = (const float*)d_in[3];
    const float* W2  = (const float*)d_in[4];
    const float* b2  = (const float*)d_in[5];
    float* out       = (float*)d_out;

    const int nz      = in_sizes[0];      // 12,800,000 (N_NODES*128)
    const int n_edges = in_sizes[1] / 2;  // 1,000,000

    const int n_groups = (n_edges + 31) / 32;
    const int stride_groups = MAIN_GRID * WAVES_PER_BLOCK;

    const size_t zh_bytes = (size_t)nz * sizeof(half_t);
    if (ws_size >= zh_bytes) {
        half_t* zh = (half_t*)d_ws;
        const int n4 = nz / 4;
        prep_z_kernel<<<(n4 + 255) / 256, 256, 0, stream>>>(z, zh, n4);
        edge_mlp_kernel<true><<<MAIN_GRID, MAIN_BLOCK, 0, stream>>>(
            z, zh, eidx, W1, b1, W2, b2, out, n_edges, n_groups, stride_groups);
    } else {
        edge_mlp_kernel<false><<<MAIN_GRID, MAIN_BLOCK, 0, stream>>>(
            z, nullptr, eidx, W1, b1, W2, b2, out, n_edges, n_groups,
            stride_groups);
    }
}

// Round 5
// 281.021 us; speedup vs baseline: 3.1570x; 1.4159x over previous
//
#include <hip/hip_runtime.h>
#include <hip/hip_fp16.h>

typedef _Float16 half_t;
typedef __attribute__((ext_vector_type(2))) _Float16 f16x2;
typedef __attribute__((ext_vector_type(4))) _Float16 f16x4;
typedef __attribute__((ext_vector_type(8))) _Float16 f16x8;
typedef __attribute__((ext_vector_type(4))) float f32x4;

// ---------------------------------------------------------------------------
// Separable MLP: h = relu(z[src].W1a + z[dst].W1b + b1)  ->  out = h.W2 + b2
// Phase 1: Y = z @ [W1a | W1b]   (dense GEMM per NODE: 6.5 GF, no gather)
// Phase 2: per edge, stream Y[src][0:128] + Y[dst][128:256]  (pure memory)
// Y row layout is column-permuted so GEMM lanes store contiguous 16 B:
//   position j in each 128-half holds hidden index h(j) = (j&7)*16 + (j>>3).
// b1/W2 are permuted identically in the edge kernel, so it never notices.
// ---------------------------------------------------------------------------

__global__ void prep_z_kernel(const float* __restrict__ z,
                              half_t* __restrict__ zh, int n4) {
    int t = blockIdx.x * 256 + threadIdx.x;
    if (t < n4) {
        const float4 v = reinterpret_cast<const float4*>(z)[t];
        f16x4 o;
        o[0] = (_Float16)v.x; o[1] = (_Float16)v.y;
        o[2] = (_Float16)v.z; o[3] = (_Float16)v.w;
        reinterpret_cast<f16x4*>(zh)[t] = o;
    }
}

// GEMM: Y[node][0:128] = z[node] @ W1[0:128,:],  Y[node][128:256] = z @ W1[128:256,:]
// B-fragment (ks in 0..3, nt in 0..15): lane L elem j holds
//   B[k = ks*32 + (L>>4)*8 + j][ncol = nt*16 + (L&15)]
// where B[k][ncol] = W1[(ncol<128 ? k : 128+k)][ncol & 127].
template <bool F16Z>
__global__ __launch_bounds__(256, 2)
void gemm_uv_kernel(const float* __restrict__ z,
                    const half_t* __restrict__ zh,
                    const float* __restrict__ W1,
                    half_t* __restrict__ Y,
                    int n_groups, int stride_groups) {
    __shared__ __align__(16) half_t w1_lds[32768];   // 64 KB: K=128 x N=256 f16
    {
        const float4* W1v = reinterpret_cast<const float4*>(W1);
#pragma unroll
        for (int i = 0; i < 32; ++i) {
            const int q = threadIdx.x + i * 256;     // 0..8191 float4s of W1
            const int u = q * 4;                     // flat kk*128 + n0
            const int kk = u >> 7, n0 = u & 127;
            const int k = kk & 127;
            const int ncol = ((kk >> 7) << 7) | n0;  // +128 if bottom half
            const float4 w = W1v[q];
            const int ks = k >> 5, j = k & 7, Lb = ((k >> 3) & 3) * 16;
            const int nt = ncol >> 4, nl = ncol & 15;
            half_t* dst = &w1_lds[(((ks * 16 + nt) * 64 + Lb + nl) * 8) + j];
            dst[0 * 8] = (half_t)w.x;
            dst[1 * 8] = (half_t)w.y;
            dst[2 * 8] = (half_t)w.z;
            dst[3 * 8] = (half_t)w.w;
        }
    }
    __syncthreads();

    const int wave = threadIdx.x >> 6;
    const int lane = threadIdx.x & 63;
    const int nlo  = lane & 15;
    const int quad = lane >> 4;
    const f16x8* blds = reinterpret_cast<const f16x8*>(w1_lds);

    for (int g = blockIdx.x * 4 + wave; g < n_groups; g += stride_groups) {
        const int node = g * 16 + nlo;   // 16 consecutive nodes per wave

        f16x8 av[4];
        if (F16Z) {
#pragma unroll
            for (int ks = 0; ks < 4; ++ks)
                av[ks] = *reinterpret_cast<const f16x8*>(
                    zh + (size_t)node * 128 + ks * 32 + quad * 8);
        } else {
#pragma unroll
            for (int ks = 0; ks < 4; ++ks) {
                const float* p = z + (size_t)node * 128 + ks * 32 + quad * 8;
                const float4 x = reinterpret_cast<const float4*>(p)[0];
                const float4 y = reinterpret_cast<const float4*>(p)[1];
                av[ks][0] = (_Float16)x.x; av[ks][1] = (_Float16)x.y;
                av[ks][2] = (_Float16)x.z; av[ks][3] = (_Float16)x.w;
                av[ks][4] = (_Float16)y.x; av[ks][5] = (_Float16)y.y;
                av[ks][6] = (_Float16)y.z; av[ks][7] = (_Float16)y.w;
            }
        }

        f32x4 acc[16];
#pragma unroll
        for (int nt = 0; nt < 16; ++nt) acc[nt] = (f32x4){0.f, 0.f, 0.f, 0.f};

#pragma unroll
        for (int ks = 0; ks < 4; ++ks) {
            const f16x8* bp = blds + ks * 1024 + lane;
#pragma unroll
            for (int nt = 0; nt < 16; ++nt)
                acc[nt] = __builtin_amdgcn_mfma_f32_16x16x32_f16(
                    av[ks], bp[nt * 64], acc[nt], 0, 0, 0);
        }

        // C/D: row m = quad*4 + r, col = nt*16 + nlo. Lane stores its 16
        // values per row contiguously: u at Y[row][nlo*8..+8], v at +128.
#pragma unroll
        for (int r = 0; r < 4; ++r) {
            const int nr = g * 16 + quad * 4 + r;
            f16x8 up, vp;
#pragma unroll
            for (int t = 0; t < 8; ++t) {
                up[t] = (_Float16)acc[t][r];
                vp[t] = (_Float16)acc[8 + t][r];
            }
            *reinterpret_cast<f16x8*>(Y + (size_t)nr * 256 + nlo * 8) = up;
            *reinterpret_cast<f16x8*>(Y + (size_t)nr * 256 + 128 + nlo * 8) = vp;
        }
    }
}

static __device__ __forceinline__ f16x2 pair2(const f16x8& v, int p) {
    f16x2 r; r[0] = v[2 * p]; r[1] = v[2 * p + 1]; return r;
}

// Edge phase: thread-per-edge. 32 independent 16-B gathers per thread,
// packed f16 math, f32 accumulation via v_dot2_f32_f16.
__global__ __launch_bounds__(256, 4)
void edge_decode_kernel(const half_t* __restrict__ Y,
                        const int* __restrict__ eidx,
                        const float* __restrict__ b1,
                        const float* __restrict__ W2,
                        const float* __restrict__ b2,
                        float* __restrict__ out, int n_edges) {
    __shared__ __align__(16) half_t b1h[128];
    __shared__ __align__(16) half_t w2h[128];
    if (threadIdx.x < 128) {
        const int i = threadIdx.x;
        const int n = (i & 7) * 16 + (i >> 3);   // match Y's column permute
        b1h[i] = (half_t)b1[n];
        w2h[i] = (half_t)W2[n];
    }
    __syncthreads();

    const int e = blockIdx.x * 256 + threadIdx.x;
    if (e >= n_edges) return;
    const int s = eidx[e];
    const int d = eidx[n_edges + e];
    const f16x8* up = reinterpret_cast<const f16x8*>(Y + (size_t)s * 256);
    const f16x8* vp = reinterpret_cast<const f16x8*>(Y + (size_t)d * 256 + 128);
    const f16x8* bb = reinterpret_cast<const f16x8*>(b1h);
    const f16x8* ww = reinterpret_cast<const f16x8*>(w2h);

    float acc = 0.f;
    const f16x2 zero2 = {(_Float16)0, (_Float16)0};
#pragma unroll
    for (int c = 0; c < 16; ++c) {
        const f16x8 a = up[c];
        const f16x8 v = vp[c];
        const f16x8 bc = bb[c];
        const f16x8 wc = ww[c];
#pragma unroll
        for (int p = 0; p < 4; ++p) {
            f16x2 h2 = pair2(a, p) + pair2(v, p) + pair2(bc, p);
            h2 = __builtin_elementwise_max(h2, zero2);
            acc = __builtin_amdgcn_fdot2(h2, pair2(wc, p), acc, false);
        }
    }
    out[e] = acc + b2[0];
}

// Insurance fallback (only if workspace is unexpectedly tiny): correct, slow.
__global__ void naive_edge_kernel(const float* __restrict__ z,
                                  const int* __restrict__ eidx,
                                  const float* __restrict__ W1,
                                  const float* __restrict__ b1,
                                  const float* __restrict__ W2,
                                  const float* __restrict__ b2,
                                  float* __restrict__ out, int n_edges) {
    __shared__ float feat[256];
    __shared__ float red[2];
    const int e = blockIdx.x;
    const int t = threadIdx.x;           // 128 threads
    const int s = eidx[e], d = eidx[n_edges + e];
    feat[t] = z[(size_t)s * 128 + t];
    feat[128 + t] = z[(size_t)d * 128 + t];
    __syncthreads();
    float h = b1[t];
    for (int k = 0; k < 256; ++k) h = fmaf(feat[k], W1[k * 128 + t], h);
    float p = fmaxf(h, 0.f) * W2[t];
    for (int off = 32; off; off >>= 1) p += __shfl_down(p, off);
    if ((t & 63) == 0) red[t >> 6] = p;
    __syncthreads();
    if (t == 0) out[e] = red[0] + red[1] + b2[0];
}

extern "C" void kernel_launch(void* const* d_in, const int* in_sizes, int n_in,
                              void* d_out, int out_size, void* d_ws,
                              size_t ws_size, hipStream_t stream) {
    const float* z   = (const float*)d_in[0];
    const int* eidx  = (const int*)d_in[1];   // int64 ref passed as int32
    const float* W1  = (const float*)d_in[2];
    const float* b1  = (const float*)d_in[3];
    const float* W2  = (const float*)d_in[4];
    const float* b2  = (const float*)d_in[5];
    float* out       = (float*)d_out;

    const int nz      = in_sizes[0];          // 12,800,000
    const int n_nodes = nz / 128;             // 100,000
    const int n_edges = in_sizes[1] / 2;      // 1,000,000

    const size_t Y_bytes  = (size_t)n_nodes * 256 * sizeof(half_t); // 51.2 MB
    const size_t zh_bytes = (size_t)nz * sizeof(half_t);            // 25.6 MB

    const int n_groups = n_nodes / 16;        // 6250 (exact)
    const int edge_blocks = (n_edges + 255) / 256;

    if (ws_size >= Y_bytes + zh_bytes) {
        half_t* Y  = (half_t*)d_ws;
        half_t* zh = (half_t*)((char*)d_ws + Y_bytes);
        const int n4 = nz / 4;
        prep_z_kernel<<<(n4 + 255) / 256, 256, 0, stream>>>(z, zh, n4);
        gemm_uv_kernel<true><<<512, 256, 0, stream>>>(z, zh, W1, Y, n_groups,
                                                      512 * 4);
        edge_decode_kernel<<<edge_blocks, 256, 0, stream>>>(Y, eidx, b1, W2,
                                                            b2, out, n_edges);
    } else if (ws_size >= Y_bytes) {
        half_t* Y = (half_t*)d_ws;
        gemm_uv_kernel<false><<<512, 256, 0, stream>>>(z, nullptr, W1, Y,
                                                       n_groups, 512 * 4);
        edge_decode_kernel<<<edge_blocks, 256, 0, stream>>>(Y, eidx, b1, W2,
                                                            b2, out, n_edges);
    } else {
        naive_edge_kernel<<<n_edges, 128, 0, stream>>>(z, eidx, W1, b1, W2, b2,
                                                       out, n_edges);
    }
}

// Round 6
// 251.984 us; speedup vs baseline: 3.5208x; 1.1152x over previous
//
#include <hip/hip_runtime.h>
#include <hip/hip_fp16.h>

typedef _Float16 half_t;
typedef __attribute__((ext_vector_type(2))) _Float16 f16x2;
typedef __attribute__((ext_vector_type(8))) _Float16 f16x8;
typedef __attribute__((ext_vector_type(4))) float f32x4;

// ---------------------------------------------------------------------------
// Separable MLP: h = relu(z[src].W1a + z[dst].W1b + b1) ; out = h.W2 + b2
// Phase 1 (gemm_uv): Y[node] = [z[node]@W1a | z[node]@W1b]  (f16, 512 B/row)
// Phase 2 (edge_decode): out[e] = b2 + relu(Y[s][0:128]+Y[d][128:256]+b1).W2
// Y column permute: position j holds hidden index n(j) = (j&7)*16 + (j>>3);
// b1/W2 are permuted identically at staging so phase 2 is oblivious.
// ---------------------------------------------------------------------------

__global__ __launch_bounds__(256, 2)
void gemm_uv_kernel(const float* __restrict__ z,
                    const float* __restrict__ W1,
                    half_t* __restrict__ Y,
                    int n_nodes, int n_groups, int stride_groups) {
    __shared__ __align__(16) half_t w1_lds[32768];   // 64 KB: K=128 x N=256 f16
    {
        const float4* W1v = reinterpret_cast<const float4*>(W1);
#pragma unroll
        for (int i = 0; i < 32; ++i) {
            const int q = threadIdx.x + i * 256;     // 0..8191 float4s of W1
            const int u = q * 4;                     // flat kk*128 + n0
            const int kk = u >> 7, n0 = u & 127;
            const int k = kk & 127;
            const int ncol = ((kk >> 7) << 7) | n0;  // +128 if bottom half
            const float4 w = W1v[q];
            const int ks = k >> 5, j = k & 7, Lb = ((k >> 3) & 3) * 16;
            const int nt = ncol >> 4, nl = ncol & 15;
            half_t* dst = &w1_lds[(((ks * 16 + nt) * 64 + Lb + nl) * 8) + j];
            dst[0 * 8] = (half_t)w.x;
            dst[1 * 8] = (half_t)w.y;
            dst[2 * 8] = (half_t)w.z;
            dst[3 * 8] = (half_t)w.w;
        }
    }
    __syncthreads();

    const int wave = threadIdx.x >> 6;
    const int lane = threadIdx.x & 63;
    const int nlo  = lane & 15;
    const int quad = lane >> 4;
    const f16x8* blds = reinterpret_cast<const f16x8*>(w1_lds);

    for (int g = blockIdx.x * 4 + wave; g < n_groups; g += stride_groups) {
        int node = g * 16 + nlo;
        if (node >= n_nodes) node = n_nodes - 1;

        f16x8 av[4];
#pragma unroll
        for (int ks = 0; ks < 4; ++ks) {
            const float* p = z + (size_t)node * 128 + ks * 32 + quad * 8;
            const float4 x = reinterpret_cast<const float4*>(p)[0];
            const float4 y = reinterpret_cast<const float4*>(p)[1];
            av[ks][0] = (_Float16)x.x; av[ks][1] = (_Float16)x.y;
            av[ks][2] = (_Float16)x.z; av[ks][3] = (_Float16)x.w;
            av[ks][4] = (_Float16)y.x; av[ks][5] = (_Float16)y.y;
            av[ks][6] = (_Float16)y.z; av[ks][7] = (_Float16)y.w;
        }

        f32x4 acc[16];
#pragma unroll
        for (int nt = 0; nt < 16; ++nt) acc[nt] = (f32x4){0.f, 0.f, 0.f, 0.f};

#pragma unroll
        for (int ks = 0; ks < 4; ++ks) {
            const f16x8* bp = blds + ks * 1024 + lane;
#pragma unroll
            for (int nt = 0; nt < 16; ++nt)
                acc[nt] = __builtin_amdgcn_mfma_f32_16x16x32_f16(
                    av[ks], bp[nt * 64], acc[nt], 0, 0, 0);
        }

        // C/D: row m = quad*4 + r, col = nt*16 + nlo.
#pragma unroll
        for (int r = 0; r < 4; ++r) {
            const int nr = g * 16 + quad * 4 + r;
            if (nr >= n_nodes) continue;
            f16x8 up, vp;
#pragma unroll
            for (int t = 0; t < 8; ++t) {
                up[t] = (_Float16)acc[t][r];
                vp[t] = (_Float16)acc[8 + t][r];
            }
            *reinterpret_cast<f16x8*>(Y + (size_t)nr * 256 + nlo * 8) = up;
            *reinterpret_cast<f16x8*>(Y + (size_t)nr * 256 + 128 + nlo * 8) = vp;
        }
    }
}

static __device__ __forceinline__ f16x2 pair2(const f16x8& v, int p) {
    f16x2 r; r[0] = v[2 * p]; r[1] = v[2 * p + 1]; return r;
}

// Edge phase: 16 lanes per edge (4 edges/wave/iter). Lane sl loads 16 B of
// the src half and 16 B of the dst half -> every load instruction covers
// 4 x 256 B contiguous segments (8 cache lines) instead of R5's 64 random
// 16-B touches. Partial relu-dot per lane; shfl_xor reduce over 16 lanes.
__global__ __launch_bounds__(256, 8)
void edge_decode_kernel(const half_t* __restrict__ Y,
                        const int* __restrict__ eidx,
                        const float* __restrict__ b1,
                        const float* __restrict__ W2,
                        const float* __restrict__ b2,
                        float* __restrict__ out,
                        int n_edges, int stride_e) {
    __shared__ __align__(16) half_t b1h[128];
    __shared__ __align__(16) half_t w2h[128];
    if (threadIdx.x < 128) {
        const int i = threadIdx.x;
        const int n = (i & 7) * 16 + (i >> 3);   // match Y's column permute
        b1h[i] = (half_t)b1[n];
        w2h[i] = (half_t)W2[n];
    }
    __syncthreads();

    const int lane  = threadIdx.x & 63;
    const int sl    = lane & 15;    // 16-B slice within the 256-B half-row
    const int eslot = lane >> 4;    // which of the wave's 4 edges
    const f16x8 bv = reinterpret_cast<const f16x8*>(b1h)[sl];
    const f16x8 wv = reinterpret_cast<const f16x8*>(w2h)[sl];
    const float b2v = b2[0];
    const f16x2 zero2 = {(_Float16)0, (_Float16)0};

    const int w = blockIdx.x * 4 + (threadIdx.x >> 6);
    int e0 = w * 4;
    if (e0 >= n_edges) return;

    // current edge indices (prefetched one iteration ahead thereafter)
    int ec = e0 + eslot; if (ec >= n_edges) ec = 0;
    int s = eidx[ec];
    int d = eidx[n_edges + ec];

    for (; e0 < n_edges; e0 += stride_e) {
        const int e = e0 + eslot;
        const bool valid = (e < n_edges);

        const f16x8 u = *reinterpret_cast<const f16x8*>(
            Y + (size_t)s * 256 + sl * 8);
        const f16x8 v = *reinterpret_cast<const f16x8*>(
            Y + (size_t)d * 256 + 128 + sl * 8);

        // prefetch next iteration's indices
        const int en0 = e0 + stride_e;
        if (en0 < n_edges) {
            int en = en0 + eslot; if (en >= n_edges) en = 0;
            s = eidx[en];
            d = eidx[n_edges + en];
        }

        float acc = 0.f;
#pragma unroll
        for (int p = 0; p < 4; ++p) {
            f16x2 h2 = pair2(u, p) + pair2(v, p) + pair2(bv, p);
            h2 = __builtin_elementwise_max(h2, zero2);
            acc = __builtin_amdgcn_fdot2(h2, pair2(wv, p), acc, false);
        }
        acc += __shfl_xor(acc, 1);
        acc += __shfl_xor(acc, 2);
        acc += __shfl_xor(acc, 4);
        acc += __shfl_xor(acc, 8);
        if (sl == 0 && valid) out[e] = acc + b2v;
    }
}

// Insurance fallback (only if workspace is unexpectedly tiny): correct, slow.
__global__ void naive_edge_kernel(const float* __restrict__ z,
                                  const int* __restrict__ eidx,
                                  const float* __restrict__ W1,
                                  const float* __restrict__ b1,
                                  const float* __restrict__ W2,
                                  const float* __restrict__ b2,
                                  float* __restrict__ out, int n_edges) {
    __shared__ float feat[256];
    __shared__ float red[2];
    const int e = blockIdx.x;
    const int t = threadIdx.x;           // 128 threads
    const int s = eidx[e], d = eidx[n_edges + e];
    feat[t] = z[(size_t)s * 128 + t];
    feat[128 + t] = z[(size_t)d * 128 + t];
    __syncthreads();
    float h = b1[t];
    for (int k = 0; k < 256; ++k) h = fmaf(feat[k], W1[k * 128 + t], h);
    float p = fmaxf(h, 0.f) * W2[t];
    for (int off = 32; off; off >>= 1) p += __shfl_down(p, off);
    if ((t & 63) == 0) red[t >> 6] = p;
    __syncthreads();
    if (t == 0) out[e] = red[0] + red[1] + b2[0];
}

extern "C" void kernel_launch(void* const* d_in, const int* in_sizes, int n_in,
                              void* d_out, int out_size, void* d_ws,
                              size_t ws_size, hipStream_t stream) {
    const float* z   = (const float*)d_in[0];
    const int* eidx  = (const int*)d_in[1];   // int64 ref passed as int32
    const float* W1  = (const float*)d_in[2];
    const float* b1  = (const float*)d_in[3];
    const float* W2  = (const float*)d_in[4];
    const float* b2  = (const float*)d_in[5];
    float* out       = (float*)d_out;

    const int nz      = in_sizes[0];          // 12,800,000
    const int n_nodes = nz / 128;             // 100,000
    const int n_edges = in_sizes[1] / 2;      // 1,000,000

    const size_t Y_bytes = (size_t)n_nodes * 256 * sizeof(half_t); // 51.2 MB

    if (ws_size >= Y_bytes) {
        half_t* Y = (half_t*)d_ws;
        const int n_groups = (n_nodes + 15) / 16;   // 6250
        gemm_uv_kernel<<<512, 256, 0, stream>>>(z, W1, Y, n_nodes, n_groups,
                                                512 * 4);
        const int eblocks = 1024;                    // 4096 waves x 4 edges
        edge_decode_kernel<<<eblocks, 256, 0, stream>>>(
            Y, eidx, b1, W2, b2, out, n_edges, eblocks * 4 * 4);
    } else {
        naive_edge_kernel<<<n_edges, 128, 0, stream>>>(z, eidx, W1, b1, W2, b2,
                                                       out, n_edges);
    }
}